// Round 9
// baseline (336.938 us; speedup 1.0000x reference)
//
#include <hip/hip_runtime.h>
#include <hip/hip_fp16.h>

// ---------------------------------------------------------------------------
// GATv2 x2 + classifier. N=50000, E=800000, IN=128, HEADS=4, HID=32, OUT=16.
// R9: (a) gemm LDS stride 32->40 shorts (80B rows): fragment-read banks go
//     from 8-way conflict (16 lanes on 2 banks, ~2.9x) to 2-way (free);
//     (b) count_kernel node-sliced like scatter (atomics stay in one XCD's
//     L2 instead of ping-ponging cnt lines across 8 XCDs);
//     (c) csr pad-zero folded into scan_add (one fewer launch).
// ---------------------------------------------------------------------------

#define LOG2E 1.4426950408889634f
#define AST 40  // LDS row stride in shorts (was 32; 40 kills 8-way conflicts)

typedef short bf16x8 __attribute__((ext_vector_type(8)));
typedef float f32x4 __attribute__((ext_vector_type(4)));

__device__ __forceinline__ unsigned short f2bf(float f) {
  union { float f; unsigned u; } x; x.f = f;
  unsigned r = x.u + 0x7fffu + ((x.u >> 16) & 1u);
  return (unsigned short)(r >> 16);
}
__device__ __forceinline__ float bf2f(unsigned short h) {
  union { unsigned u; float f; } x; x.u = ((unsigned)h) << 16;
  return x.f;
}
__device__ __forceinline__ void split4(float4 v, ushort4& h, ushort4& l) {
  h.x = f2bf(v.x); l.x = f2bf(v.x - bf2f(h.x));
  h.y = f2bf(v.y); l.y = f2bf(v.y - bf2f(h.y));
  h.z = f2bf(v.z); l.z = f2bf(v.z - bf2f(h.z));
  h.w = f2bf(v.w); l.w = f2bf(v.w - bf2f(h.w));
}

// ------------------------------ CSR build ----------------------------------

__global__ __launch_bounds__(256) void zero_i32(int* __restrict__ p, int n) {
  int i = blockIdx.x * 256 + threadIdx.x;
  if (i < n) p[i] = 0;
}

// node-sliced count: slice = blockIdx&7 (XCD round-robin heuristic)
__global__ __launch_bounds__(256) void count_kernel(const int* __restrict__ dst,
                                                    int* __restrict__ cnt,
                                                    int E, int sliceSize) {
  int slice = blockIdx.x & 7;
  int chunk = blockIdx.x >> 3;
  int nchunk = gridDim.x >> 3;
  int lo = slice * sliceSize, hi = lo + sliceSize;
  int per = (E + nchunk - 1) / nchunk;
  int b = chunk * per;
  int e = min(b + per, E);
  for (int i = b + threadIdx.x; i < e; i += 256) {
    int d = dst[i];
    if (d >= lo && d < hi) atomicAdd(&cnt[d], 1);
  }
}

// per-block scan of (cnt[i]+1)  (+1 = self loop slot)
__global__ __launch_bounds__(256) void scan_blk(const int* __restrict__ cnt,
                                                int* __restrict__ excl,
                                                int* __restrict__ bsum, int n) {
  __shared__ int s[256];
  int t = threadIdx.x, i = blockIdx.x * 256 + t;
  int v = (i < n) ? (cnt[i] + 1) : 0;
  s[t] = v;
  __syncthreads();
#pragma unroll
  for (int off = 1; off < 256; off <<= 1) {
    int u = (t >= off) ? s[t - off] : 0;
    __syncthreads();
    s[t] += u;
    __syncthreads();
  }
  if (i < n) excl[i] = s[t] - v;
  if (t == 255) bsum[blockIdx.x] = s[255];
}

__global__ __launch_bounds__(256) void scan_bsum(int* __restrict__ bsum, int nb,
                                                 int* __restrict__ row_start, int n) {
  __shared__ int s[256];
  int t = threadIdx.x;
  int v = (t < nb) ? bsum[t] : 0;
  s[t] = v;
  __syncthreads();
#pragma unroll
  for (int off = 1; off < 256; off <<= 1) {
    int u = (t >= off) ? s[t - off] : 0;
    __syncthreads();
    s[t] += u;
    __syncthreads();
  }
  if (t < nb) bsum[t] = s[t] - v;
  if (t == 255) row_start[n] = s[255];
}

// add block offsets; write self-loop entry; wpos starts past it; zero csr pad
__global__ __launch_bounds__(256) void scan_add(int* __restrict__ row_start,
                                                const int* __restrict__ bsum,
                                                int* __restrict__ wpos,
                                                int* __restrict__ csr,
                                                int n, int padBase) {
  int i = blockIdx.x * 256 + threadIdx.x;
  if (i < n) {
    int r = row_start[i] + bsum[blockIdx.x];
    row_start[i] = r;
    wpos[i] = r + 1;
    csr[r] = i;  // self loop first in each row
  }
  if (blockIdx.x == 0 && threadIdx.x < 16) csr[padBase + threadIdx.x] = 0;
}

// node-sliced scatter (8 slices; csr slice ~400KB stays in one XCD's L2)
__global__ __launch_bounds__(256) void scatter_kernel(const int* __restrict__ src,
                                                      const int* __restrict__ dst,
                                                      int* __restrict__ wpos,
                                                      int* __restrict__ csr,
                                                      int E, int sliceSize) {
  int slice = blockIdx.x & 7;
  int chunk = blockIdx.x >> 3;
  int nchunk = gridDim.x >> 3;
  int lo = slice * sliceSize, hi = lo + sliceSize;
  int per = (E + nchunk - 1) / nchunk;
  int b = chunk * per;
  int e = min(b + per, E);
  for (int i = b + threadIdx.x; i < e; i += 256) {
    int d = dst[i];
    if (d >= lo && d < hi) {
      int p = atomicAdd(&wpos[d], 1);
      csr[p] = src[i];
    }
  }
}

// --------------------------- weight converts -------------------------------
__global__ __launch_bounds__(256) void convert_W(const float* __restrict__ Wl1,
                                                 const float* __restrict__ Wr1,
                                                 const float* __restrict__ Wl2,
                                                 const float* __restrict__ Wr2,
                                                 unsigned short* __restrict__ BT1h,
                                                 unsigned short* __restrict__ BT1l,
                                                 unsigned short* __restrict__ BT2h,
                                                 unsigned short* __restrict__ BT2l) {
  int b = blockIdx.x;
  const float* Wl = (b < 128) ? Wl1 : Wl2;
  const float* Wr = (b < 128) ? Wr1 : Wr2;
  unsigned short* BTh = (b < 128) ? BT1h : BT2h;
  unsigned short* BTl = (b < 128) ? BT1l : BT2l;
  int idx = (b & 127) * 256 + threadIdx.x;  // 0..32767
  int col = idx >> 7, k = idx & 127;
  float v = (col < 128) ? Wl[k * 128 + col] : Wr[k * 128 + (col - 128)];
  unsigned short h = f2bf(v);
  BTh[idx] = h;
  BTl[idx] = f2bf(v - bf2f(h));
}

// ------------------------------ MFMA GEMM ----------------------------------
// C[N x 256] = A[N x 128] @ W[128 x 256], split-bf16 3-term; C stored fp16.
// LDS rows padded to AST=40 shorts (80B): fragment reads are 2-way (free).
template <bool FP32IN>
__global__ __launch_bounds__(256) void gemm_mfma(
    const float* __restrict__ Af,
    const unsigned short* __restrict__ Ah, const unsigned short* __restrict__ Al,
    const unsigned short* __restrict__ BTh, const unsigned short* __restrict__ BTl,
    __half* __restrict__ Cl, __half* __restrict__ Cr, int nrows) {
  __shared__ unsigned short sAh[128 * AST], sAl[128 * AST];
  __shared__ unsigned short sBh[64 * AST], sBl[64 * AST];
  int tid = threadIdx.x;
  int wave = tid >> 6, lane = tid & 63;
  int rowBase = blockIdx.x * 128;
  int colBase = blockIdx.y * 64;
  int rowHalf = (wave >> 1) * 64;
  int colHalf = (wave & 1) * 32;
  int l15 = lane & 15, quad = lane >> 4;

  f32x4 acc[4][2];
#pragma unroll
  for (int m = 0; m < 4; ++m)
#pragma unroll
    for (int n = 0; n < 2; ++n) acc[m][n] = (f32x4){0.f, 0.f, 0.f, 0.f};

  for (int kc = 0; kc < 4; ++kc) {
#pragma unroll
    for (int i = 0; i < 2; ++i) {
      int idx = tid + i * 256;  // 0..511
      int row = idx >> 2, seg = idx & 3;
      int gr = rowBase + row;
      if (FP32IN) {
        float4 v0 = make_float4(0.f, 0.f, 0.f, 0.f), v1 = v0;
        if (gr < nrows) {
          v0 = *(const float4*)&Af[(size_t)gr * 128 + kc * 32 + seg * 8];
          v1 = *(const float4*)&Af[(size_t)gr * 128 + kc * 32 + seg * 8 + 4];
        }
        ushort4 h0, l0, h1, l1;
        split4(v0, h0, l0);
        split4(v1, h1, l1);
        *(ushort4*)&sAh[row * AST + seg * 8] = h0;
        *(ushort4*)&sAh[row * AST + seg * 8 + 4] = h1;
        *(ushort4*)&sAl[row * AST + seg * 8] = l0;
        *(ushort4*)&sAl[row * AST + seg * 8 + 4] = l1;
      } else {
        uint4 vh = make_uint4(0, 0, 0, 0), vl = make_uint4(0, 0, 0, 0);
        if (gr < nrows) {
          vh = *(const uint4*)&Ah[(size_t)gr * 128 + kc * 32 + seg * 8];
          vl = *(const uint4*)&Al[(size_t)gr * 128 + kc * 32 + seg * 8];
        }
        *(uint4*)&sAh[row * AST + seg * 8] = vh;
        *(uint4*)&sAl[row * AST + seg * 8] = vl;
      }
    }
    {
      int col = tid >> 2, seg = tid & 3;
      *(uint4*)&sBh[col * AST + seg * 8] =
          *(const uint4*)&BTh[(size_t)(colBase + col) * 128 + kc * 32 + seg * 8];
      *(uint4*)&sBl[col * AST + seg * 8] =
          *(const uint4*)&BTl[(size_t)(colBase + col) * 128 + kc * 32 + seg * 8];
    }
    __syncthreads();

    bf16x8 afh[4], afl[4], bfh[2], bfl[2];
#pragma unroll
    for (int m = 0; m < 4; ++m) {
      int r = rowHalf + m * 16 + l15;
      afh[m] = *(const bf16x8*)&sAh[r * AST + quad * 8];
      afl[m] = *(const bf16x8*)&sAl[r * AST + quad * 8];
    }
#pragma unroll
    for (int n = 0; n < 2; ++n) {
      int cc = colHalf + n * 16 + l15;
      bfh[n] = *(const bf16x8*)&sBh[cc * AST + quad * 8];
      bfl[n] = *(const bf16x8*)&sBl[cc * AST + quad * 8];
    }
#pragma unroll
    for (int m = 0; m < 4; ++m)
#pragma unroll
      for (int n = 0; n < 2; ++n) {
        acc[m][n] = __builtin_amdgcn_mfma_f32_16x16x32_bf16(afh[m], bfh[n], acc[m][n], 0, 0, 0);
        acc[m][n] = __builtin_amdgcn_mfma_f32_16x16x32_bf16(afh[m], bfl[n], acc[m][n], 0, 0, 0);
        acc[m][n] = __builtin_amdgcn_mfma_f32_16x16x32_bf16(afl[m], bfh[n], acc[m][n], 0, 0, 0);
      }
    __syncthreads();
  }

  bool isL = (colBase < 128);
  __half* __restrict__ C = isL ? Cl : Cr;
  int cb = (isL ? colBase : colBase - 128) + colHalf;
#pragma unroll
  for (int m = 0; m < 4; ++m)
#pragma unroll
    for (int r = 0; r < 4; ++r) {
      int grow = rowBase + rowHalf + m * 16 + quad * 4 + r;
      if (grow < nrows) {
#pragma unroll
        for (int n = 0; n < 2; ++n)
          C[(size_t)grow * 128 + cb + n * 16 + l15] = __float2half(acc[m][n][r]);
      }
    }
}

// ------------------------------ attention ----------------------------------
// One wave per node; 16 lanes/edge (8 ch/lane, one b128 fp16 load);
// 4 edge-slots/wave. Main loop 16 edges/iter, tail 4 edges/iter.
// Self loop lives in csr (csr[beg] = node).
__global__ __launch_bounds__(256) void gat_attn(const __half* __restrict__ xl,
                                                const __half* __restrict__ xr,
                                                const int* __restrict__ row_start,
                                                const int* __restrict__ csr,
                                                const float* __restrict__ att,
                                                const float* __restrict__ bias,
                                                float* __restrict__ ofp,
                                                unsigned short* __restrict__ oh_hi,
                                                unsigned short* __restrict__ oh_lo,
                                                int n_nodes) {
  int node = blockIdx.x * 4 + (threadIdx.x >> 6);
  if (node >= n_nodes) return;
  int lane = threadIdx.x & 63;
  int slot = lane >> 4;
  int l15 = lane & 15;
  int c0 = l15 * 8;

  // xr row (fp16 -> fp32)
  float fxr[8];
  {
    uint4 raw = *(const uint4*)&xr[(size_t)node * 128 + c0];
    const __half* hp = (const __half*)&raw;
#pragma unroll
    for (int k = 0; k < 8; ++k) fxr[k] = __half2float(hp[k]);
  }
  // att row, pre-scaled: a06 = 0.6*log2e*a, a04 = 0.4*log2e*a
  float a06[8], a04[8];
  {
    float4 a0 = *(const float4*)&att[c0];
    float4 a1 = *(const float4*)&att[c0 + 4];
    float av[8] = {a0.x, a0.y, a0.z, a0.w, a1.x, a1.y, a1.z, a1.w};
    const float C06 = 0.6f * LOG2E, C04 = 0.4f * LOG2E;
#pragma unroll
    for (int k = 0; k < 8; ++k) { a06[k] = av[k] * C06; a04[k] = av[k] * C04; }
  }

  float acc[8];
#pragma unroll
  for (int k = 0; k < 8; ++k) acc[k] = 0.f;
  float lsum = 0.f;

#define EDGE_BODY(SRC, PVALID)                                                 \
  {                                                                            \
    uint4 raw = *(const uint4*)&xl[(size_t)(unsigned)(SRC)*128 + c0];          \
    const __half* hp = (const __half*)&raw;                                    \
    float e = 0.f;                                                             \
    _Pragma("unroll") for (int k = 0; k < 8; ++k) {                            \
      float t = __half2float(hp[k]) + fxr[k];                                  \
      e = fmaf(a06[k], t, e);                                                  \
      e = fmaf(a04[k], fabsf(t), e);                                           \
    }                                                                          \
    e += __shfl_xor(e, 1);                                                     \
    e += __shfl_xor(e, 2);                                                     \
    float p = (PVALID) ? __builtin_amdgcn_exp2f(e) : 0.f;                      \
    lsum += p;                                                                 \
    _Pragma("unroll") for (int k = 0; k < 8; ++k)                              \
        acc[k] = fmaf(p, __half2float(hp[k]), acc[k]);                         \
  }

  int beg = row_start[node], end = row_start[node + 1];
  int deg = end - beg;  // includes self
  int fullEnd = beg + (deg & ~15);

  for (int base = beg; base < fullEnd; base += 16) {
    int b0 = base + 4 * slot;
    int s0 = csr[b0], s1 = csr[b0 + 1], s2 = csr[b0 + 2], s3 = csr[b0 + 3];
    EDGE_BODY(s0, true);
    EDGE_BODY(s1, true);
    EDGE_BODY(s2, true);
    EDGE_BODY(s3, true);
  }
  for (int base = fullEnd; base < end; base += 4) {  // csr padded by 16
    int idx = base + slot;
    int src = csr[idx];
    EDGE_BODY(src, idx < end);
  }
#undef EDGE_BODY

  // merge the 4 slots (same channels live in lanes with equal l15)
  lsum += __shfl_xor(lsum, 16);
  lsum += __shfl_xor(lsum, 32);
#pragma unroll
  for (int k = 0; k < 8; ++k) {
    acc[k] += __shfl_xor(acc[k], 16);
    acc[k] += __shfl_xor(acc[k], 32);
  }

  if (slot == 0) {
    float4 b0v = *(const float4*)&bias[c0];
    float4 b1v = *(const float4*)&bias[c0 + 4];
    float bv[8] = {b0v.x, b0v.y, b0v.z, b0v.w, b1v.x, b1v.y, b1v.z, b1v.w};
    float inv = 1.f / (lsum + 1e-16f);
    float o[8];
#pragma unroll
    for (int k = 0; k < 8; ++k) {
      float v = fmaf(acc[k], inv, bv[k]);
      o[k] = fmaf(0.495f, fabsf(v), 0.505f * v);  // leaky 0.01
    }
    if (ofp) {
      *(float4*)&ofp[(size_t)node * 128 + c0] = make_float4(o[0], o[1], o[2], o[3]);
      *(float4*)&ofp[(size_t)node * 128 + c0 + 4] = make_float4(o[4], o[5], o[6], o[7]);
    }
    if (oh_hi) {
      ushort4 h0, l0, h1, l1;
      split4(make_float4(o[0], o[1], o[2], o[3]), h0, l0);
      split4(make_float4(o[4], o[5], o[6], o[7]), h1, l1);
      *(ushort4*)&oh_hi[(size_t)node * 128 + c0] = h0;
      *(ushort4*)&oh_hi[(size_t)node * 128 + c0 + 4] = h1;
      *(ushort4*)&oh_lo[(size_t)node * 128 + c0] = l0;
      *(ushort4*)&oh_lo[(size_t)node * 128 + c0 + 4] = l1;
    }
  }
}

// ------------------------------ classifier ---------------------------------
__global__ __launch_bounds__(256) void classifier_kernel(const float4* __restrict__ h4,
                                                         const float* __restrict__ Wc,
                                                         const float* __restrict__ bc,
                                                         float* __restrict__ logits,
                                                         int n) {
  __shared__ float sW[2048];
  __shared__ float sb[16];
  int t = threadIdx.x;
#pragma unroll
  for (int i = 0; i < 8; ++i) sW[t + i * 256] = Wc[t + i * 256];
  if (t < 16) sb[t] = bc[t];
  __syncthreads();
  int node = blockIdx.x * 256 + t;
  if (node >= n) return;
  float acc[16];
#pragma unroll
  for (int o = 0; o < 16; ++o) acc[o] = sb[o];
  for (int c4 = 0; c4 < 32; ++c4) {
    float4 hv = h4[(unsigned)node * 32 + c4];
    const float* w = &sW[c4 * 64];
#pragma unroll
    for (int o = 0; o < 16; ++o) {
      acc[o] = fmaf(hv.x, w[o], acc[o]);
      acc[o] = fmaf(hv.y, w[16 + o], acc[o]);
      acc[o] = fmaf(hv.z, w[32 + o], acc[o]);
      acc[o] = fmaf(hv.w, w[48 + o], acc[o]);
    }
  }
#pragma unroll
  for (int q = 0; q < 4; ++q)
    *(float4*)&logits[(size_t)node * 16 + q * 4] =
        make_float4(acc[q * 4], acc[q * 4 + 1], acc[q * 4 + 2], acc[q * 4 + 3]);
}

// ---------------------------------------------------------------------------

extern "C" void kernel_launch(void* const* d_in, const int* in_sizes, int n_in,
                              void* d_out, int out_size, void* d_ws, size_t ws_size,
                              hipStream_t stream) {
  const float* x    = (const float*)d_in[0];
  const int*   ei   = (const int*)d_in[1];
  const float* Wl1  = (const float*)d_in[3];
  const float* Wr1  = (const float*)d_in[4];
  const float* att1 = (const float*)d_in[5];
  const float* b1   = (const float*)d_in[6];
  const float* Wl2  = (const float*)d_in[7];
  const float* Wr2  = (const float*)d_in[8];
  const float* att2 = (const float*)d_in[9];
  const float* b2   = (const float*)d_in[10];
  const float* Wc   = (const float*)d_in[11];
  const float* bc   = (const float*)d_in[12];

  const int N = in_sizes[0] / 128;
  const int E = in_sizes[1] / 2;

  float* outp   = (float*)d_out;
  float* logits = outp;                   // N*16 fp32
  float* hout   = outp + (size_t)N * 16;  // N*128 fp32 region
  // h1 bf16 hi/lo staged in the hout region (overwritten by fp32 h2 later)
  unsigned short* regionA = (unsigned short*)hout;
  unsigned short* regionB = regionA + (size_t)N * 128;

  char* ws = (char*)d_ws;
  __half* xlbuf = (__half*)ws;                ws += (size_t)N * 128 * 2;
  __half* xrbuf = (__half*)ws;                ws += (size_t)N * 128 * 2;
  unsigned short* WT1h = (unsigned short*)ws; ws += 256 * 128 * 2;
  unsigned short* WT1l = (unsigned short*)ws; ws += 256 * 128 * 2;
  unsigned short* WT2h = (unsigned short*)ws; ws += 256 * 128 * 2;
  unsigned short* WT2l = (unsigned short*)ws; ws += 256 * 128 * 2;
  int* cnt       = (int*)ws;                  ws += (size_t)N * 4;
  int* row_start = (int*)ws;                  ws += (size_t)(N + 1) * 4;
  int* wpos      = (int*)ws;                  ws += (size_t)N * 4;
  int* bsum      = (int*)ws;                  ws += 256 * 4;
  int* csr       = (int*)ws;                  ws += (size_t)(E + N + 16) * 4;

  const int* esrc = ei;
  const int* edst = ei + E;

  int gN = (N + 255) / 256;
  dim3 gGemm((N + 127) / 128, 4);
  int gAttn = (N + 3) / 4;
  int sliceSize = (N + 7) / 8;

  // CSR build (self loops embedded: counts+1, csr[beg]=node)
  zero_i32<<<gN, 256, 0, stream>>>(cnt, N);
  count_kernel<<<1024, 256, 0, stream>>>(edst, cnt, E, sliceSize);
  scan_blk<<<gN, 256, 0, stream>>>(cnt, row_start, bsum, N);
  scan_bsum<<<1, 256, 0, stream>>>(bsum, gN, row_start, N);
  scan_add<<<gN, 256, 0, stream>>>(row_start, bsum, wpos, csr, N, E + N);
  scatter_kernel<<<1024, 256, 0, stream>>>(esrc, edst, wpos, csr, E, sliceSize);

  // weight conversions (both layers, one dispatch)
  convert_W<<<256, 256, 0, stream>>>(Wl1, Wr1, Wl2, Wr2, WT1h, WT1l, WT2h, WT2l);

  // layer 1 (GEMM reads fp32 x, splits inline; writes fp16 xl/xr)
  gemm_mfma<true><<<gGemm, 256, 0, stream>>>(x, nullptr, nullptr, WT1h, WT1l,
                                             xlbuf, xrbuf, N);
  gat_attn<<<gAttn, 256, 0, stream>>>(xlbuf, xrbuf, row_start, csr, att1, b1,
                                      nullptr, regionA, regionB, N);

  // layer 2 (reads h1 bf16 hi/lo; writes fp16 xl/xr)
  gemm_mfma<false><<<gGemm, 256, 0, stream>>>(nullptr, regionA, regionB, WT2h, WT2l,
                                              xlbuf, xrbuf, N);
  gat_attn<<<gAttn, 256, 0, stream>>>(xlbuf, xrbuf, row_start, csr, att2, b2,
                                      hout, nullptr, nullptr, N);

  // classifier
  classifier_kernel<<<(N + 255) / 256, 256, 0, stream>>>((const float4*)hout, Wc, bc,
                                                         logits, N);
}

// Round 10
// 325.738 us; speedup vs baseline: 1.0344x; 1.0344x over previous
//
#include <hip/hip_runtime.h>
#include <hip/hip_fp16.h>

// ---------------------------------------------------------------------------
// GATv2 x2 + classifier. N=50000, E=800000, IN=128, HEADS=4, HID=32, OUT=16.
// R10: (a) count reverted to simple 1-pass (R9 slicing added 8x dst re-reads
//      for a kernel whose write set is only 200KB -- regression);
//      (b) gemm y-blocks 4->2: 128x128 per block, A staged once per 2 col
//      halves (half the staging/barriers per MFMA), 41KB LDS, 782 blocks;
//      (c) h1 stored fp16 single-buffer (attn1 write & gemm2 read halved),
//      gemm2 splits fp16->bf16 hi/lo inline during staging.
// ---------------------------------------------------------------------------

#define LOG2E 1.4426950408889634f
#define AST 40  // LDS row stride in shorts (80B rows; fragment reads 2-way=free)

typedef short bf16x8 __attribute__((ext_vector_type(8)));
typedef float f32x4 __attribute__((ext_vector_type(4)));

__device__ __forceinline__ unsigned short f2bf(float f) {
  union { float f; unsigned u; } x; x.f = f;
  unsigned r = x.u + 0x7fffu + ((x.u >> 16) & 1u);
  return (unsigned short)(r >> 16);
}
__device__ __forceinline__ float bf2f(unsigned short h) {
  union { unsigned u; float f; } x; x.u = ((unsigned)h) << 16;
  return x.f;
}
__device__ __forceinline__ void split4(float4 v, ushort4& h, ushort4& l) {
  h.x = f2bf(v.x); l.x = f2bf(v.x - bf2f(h.x));
  h.y = f2bf(v.y); l.y = f2bf(v.y - bf2f(h.y));
  h.z = f2bf(v.z); l.z = f2bf(v.z - bf2f(h.z));
  h.w = f2bf(v.w); l.w = f2bf(v.w - bf2f(h.w));
}

// ------------------------------ CSR build ----------------------------------

__global__ __launch_bounds__(256) void zero_i32(int* __restrict__ p, int n) {
  int i = blockIdx.x * 256 + threadIdx.x;
  if (i < n) p[i] = 0;
}

__global__ __launch_bounds__(256) void count_kernel(const int* __restrict__ dst,
                                                    int* __restrict__ cnt, int E) {
  int i = blockIdx.x * 256 + threadIdx.x;
  if (i < E) atomicAdd(&cnt[dst[i]], 1);
}

// per-block scan of (cnt[i]+1)  (+1 = self loop slot)
__global__ __launch_bounds__(256) void scan_blk(const int* __restrict__ cnt,
                                                int* __restrict__ excl,
                                                int* __restrict__ bsum, int n) {
  __shared__ int s[256];
  int t = threadIdx.x, i = blockIdx.x * 256 + t;
  int v = (i < n) ? (cnt[i] + 1) : 0;
  s[t] = v;
  __syncthreads();
#pragma unroll
  for (int off = 1; off < 256; off <<= 1) {
    int u = (t >= off) ? s[t - off] : 0;
    __syncthreads();
    s[t] += u;
    __syncthreads();
  }
  if (i < n) excl[i] = s[t] - v;
  if (t == 255) bsum[blockIdx.x] = s[255];
}

__global__ __launch_bounds__(256) void scan_bsum(int* __restrict__ bsum, int nb,
                                                 int* __restrict__ row_start, int n) {
  __shared__ int s[256];
  int t = threadIdx.x;
  int v = (t < nb) ? bsum[t] : 0;
  s[t] = v;
  __syncthreads();
#pragma unroll
  for (int off = 1; off < 256; off <<= 1) {
    int u = (t >= off) ? s[t - off] : 0;
    __syncthreads();
    s[t] += u;
    __syncthreads();
  }
  if (t < nb) bsum[t] = s[t] - v;
  if (t == 255) row_start[n] = s[255];
}

// add block offsets; write self-loop entry; wpos starts past it; zero csr pad
__global__ __launch_bounds__(256) void scan_add(int* __restrict__ row_start,
                                                const int* __restrict__ bsum,
                                                int* __restrict__ wpos,
                                                int* __restrict__ csr,
                                                int n, int padBase) {
  int i = blockIdx.x * 256 + threadIdx.x;
  if (i < n) {
    int r = row_start[i] + bsum[blockIdx.x];
    row_start[i] = r;
    wpos[i] = r + 1;
    csr[r] = i;  // self loop first in each row
  }
  if (blockIdx.x == 0 && threadIdx.x < 16) csr[padBase + threadIdx.x] = 0;
}

// node-sliced scatter (8 slices; csr slice ~400KB stays in one XCD's L2 so
// the random 4B csr writes combine -- this was the R8 win, keep it)
__global__ __launch_bounds__(256) void scatter_kernel(const int* __restrict__ src,
                                                      const int* __restrict__ dst,
                                                      int* __restrict__ wpos,
                                                      int* __restrict__ csr,
                                                      int E, int sliceSize) {
  int slice = blockIdx.x & 7;
  int chunk = blockIdx.x >> 3;
  int nchunk = gridDim.x >> 3;
  int lo = slice * sliceSize, hi = lo + sliceSize;
  int per = (E + nchunk - 1) / nchunk;
  int b = chunk * per;
  int e = min(b + per, E);
  for (int i = b + threadIdx.x; i < e; i += 256) {
    int d = dst[i];
    if (d >= lo && d < hi) {
      int p = atomicAdd(&wpos[d], 1);
      csr[p] = src[i];
    }
  }
}

// --------------------------- weight converts -------------------------------
__global__ __launch_bounds__(256) void convert_W(const float* __restrict__ Wl1,
                                                 const float* __restrict__ Wr1,
                                                 const float* __restrict__ Wl2,
                                                 const float* __restrict__ Wr2,
                                                 unsigned short* __restrict__ BT1h,
                                                 unsigned short* __restrict__ BT1l,
                                                 unsigned short* __restrict__ BT2h,
                                                 unsigned short* __restrict__ BT2l) {
  int b = blockIdx.x;
  const float* Wl = (b < 128) ? Wl1 : Wl2;
  const float* Wr = (b < 128) ? Wr1 : Wr2;
  unsigned short* BTh = (b < 128) ? BT1h : BT2h;
  unsigned short* BTl = (b < 128) ? BT1l : BT2l;
  int idx = (b & 127) * 256 + threadIdx.x;  // 0..32767
  int col = idx >> 7, k = idx & 127;
  float v = (col < 128) ? Wl[k * 128 + col] : Wr[k * 128 + (col - 128)];
  unsigned short h = f2bf(v);
  BTh[idx] = h;
  BTl[idx] = f2bf(v - bf2f(h));
}

// ------------------------------ MFMA GEMM ----------------------------------
// C[N x 256] = A[N x 128] @ W[128 x 256], split-bf16 3-term; C stored fp16.
// Block = 128 rows x 128 cols (blockIdx.y in {0,1} picks Cl / Cr half).
// 4 waves, each 64x64 (16 acc tiles). A staged once per 128 output cols.
enum { IN_F32 = 0, IN_F16 = 1 };
template <int MODE>
__global__ __launch_bounds__(256) void gemm_mfma(
    const float* __restrict__ Af, const __half* __restrict__ Af16,
    const unsigned short* __restrict__ BTh, const unsigned short* __restrict__ BTl,
    __half* __restrict__ Cl, __half* __restrict__ Cr, int nrows) {
  __shared__ unsigned short sAh[128 * AST], sAl[128 * AST];
  __shared__ unsigned short sBh[128 * AST], sBl[128 * AST];
  int tid = threadIdx.x;
  int wave = tid >> 6, lane = tid & 63;
  int rowBase = blockIdx.x * 128;
  int colBase = blockIdx.y * 128;
  int rowHalf = (wave >> 1) * 64;
  int colHalf = (wave & 1) * 64;
  int l15 = lane & 15, quad = lane >> 4;

  f32x4 acc[4][4];
#pragma unroll
  for (int m = 0; m < 4; ++m)
#pragma unroll
    for (int n = 0; n < 4; ++n) acc[m][n] = (f32x4){0.f, 0.f, 0.f, 0.f};

  for (int kc = 0; kc < 4; ++kc) {
    // stage A: 128 rows x 32 k (hi+lo); idx 0..511, 8 k-elems each
#pragma unroll
    for (int i = 0; i < 2; ++i) {
      int idx = tid + i * 256;
      int row = idx >> 2, seg = idx & 3;
      int gr = rowBase + row;
      if (MODE == IN_F32) {
        float4 v0 = make_float4(0.f, 0.f, 0.f, 0.f), v1 = v0;
        if (gr < nrows) {
          v0 = *(const float4*)&Af[(size_t)gr * 128 + kc * 32 + seg * 8];
          v1 = *(const float4*)&Af[(size_t)gr * 128 + kc * 32 + seg * 8 + 4];
        }
        ushort4 h0, l0, h1, l1;
        split4(v0, h0, l0);
        split4(v1, h1, l1);
        *(ushort4*)&sAh[row * AST + seg * 8] = h0;
        *(ushort4*)&sAh[row * AST + seg * 8 + 4] = h1;
        *(ushort4*)&sAl[row * AST + seg * 8] = l0;
        *(ushort4*)&sAl[row * AST + seg * 8 + 4] = l1;
      } else {
        uint4 raw = make_uint4(0, 0, 0, 0);
        if (gr < nrows)
          raw = *(const uint4*)&Af16[(size_t)gr * 128 + kc * 32 + seg * 8];
        const __half* hp = (const __half*)&raw;
        float4 v0 = make_float4(__half2float(hp[0]), __half2float(hp[1]),
                                __half2float(hp[2]), __half2float(hp[3]));
        float4 v1 = make_float4(__half2float(hp[4]), __half2float(hp[5]),
                                __half2float(hp[6]), __half2float(hp[7]));
        ushort4 h0, l0, h1, l1;
        split4(v0, h0, l0);
        split4(v1, h1, l1);
        *(ushort4*)&sAh[row * AST + seg * 8] = h0;
        *(ushort4*)&sAh[row * AST + seg * 8 + 4] = h1;
        *(ushort4*)&sAl[row * AST + seg * 8] = l0;
        *(ushort4*)&sAl[row * AST + seg * 8 + 4] = l1;
      }
    }
    // stage B: 128 cols x 32 k (hi+lo); idx 0..511
#pragma unroll
    for (int i = 0; i < 2; ++i) {
      int idx = tid + i * 256;
      int col = idx >> 2, seg = idx & 3;
      *(uint4*)&sBh[col * AST + seg * 8] =
          *(const uint4*)&BTh[(size_t)(colBase + col) * 128 + kc * 32 + seg * 8];
      *(uint4*)&sBl[col * AST + seg * 8] =
          *(const uint4*)&BTl[(size_t)(colBase + col) * 128 + kc * 32 + seg * 8];
    }
    __syncthreads();

    bf16x8 afh[4], afl[4], bfh[4], bfl[4];
#pragma unroll
    for (int m = 0; m < 4; ++m) {
      int r = rowHalf + m * 16 + l15;
      afh[m] = *(const bf16x8*)&sAh[r * AST + quad * 8];
      afl[m] = *(const bf16x8*)&sAl[r * AST + quad * 8];
    }
#pragma unroll
    for (int n = 0; n < 4; ++n) {
      int cc = colHalf + n * 16 + l15;
      bfh[n] = *(const bf16x8*)&sBh[cc * AST + quad * 8];
      bfl[n] = *(const bf16x8*)&sBl[cc * AST + quad * 8];
    }
#pragma unroll
    for (int m = 0; m < 4; ++m)
#pragma unroll
      for (int n = 0; n < 4; ++n) {
        acc[m][n] = __builtin_amdgcn_mfma_f32_16x16x32_bf16(afh[m], bfh[n], acc[m][n], 0, 0, 0);
        acc[m][n] = __builtin_amdgcn_mfma_f32_16x16x32_bf16(afh[m], bfl[n], acc[m][n], 0, 0, 0);
        acc[m][n] = __builtin_amdgcn_mfma_f32_16x16x32_bf16(afl[m], bfh[n], acc[m][n], 0, 0, 0);
      }
    __syncthreads();
  }

  __half* __restrict__ C = (blockIdx.y == 0) ? Cl : Cr;
#pragma unroll
  for (int m = 0; m < 4; ++m)
#pragma unroll
    for (int r = 0; r < 4; ++r) {
      int grow = rowBase + rowHalf + m * 16 + quad * 4 + r;
      if (grow < nrows) {
#pragma unroll
        for (int n = 0; n < 4; ++n)
          C[(size_t)grow * 128 + colHalf + n * 16 + l15] = __float2half(acc[m][n][r]);
      }
    }
}

// ------------------------------ attention ----------------------------------
// One wave per node; 16 lanes/edge (8 ch/lane, one b128 fp16 load);
// 4 edge-slots/wave. Main loop 16 edges/iter, tail 4 edges/iter.
// Self loop lives in csr (csr[beg] = node). Outputs fp32 and/or fp16.
__global__ __launch_bounds__(256) void gat_attn(const __half* __restrict__ xl,
                                                const __half* __restrict__ xr,
                                                const int* __restrict__ row_start,
                                                const int* __restrict__ csr,
                                                const float* __restrict__ att,
                                                const float* __restrict__ bias,
                                                float* __restrict__ ofp,
                                                __half* __restrict__ oh16,
                                                int n_nodes) {
  int node = blockIdx.x * 4 + (threadIdx.x >> 6);
  if (node >= n_nodes) return;
  int lane = threadIdx.x & 63;
  int slot = lane >> 4;
  int l15 = lane & 15;
  int c0 = l15 * 8;

  // xr row (fp16 -> fp32)
  float fxr[8];
  {
    uint4 raw = *(const uint4*)&xr[(size_t)node * 128 + c0];
    const __half* hp = (const __half*)&raw;
#pragma unroll
    for (int k = 0; k < 8; ++k) fxr[k] = __half2float(hp[k]);
  }
  // att row, pre-scaled: a06 = 0.6*log2e*a, a04 = 0.4*log2e*a
  float a06[8], a04[8];
  {
    float4 a0 = *(const float4*)&att[c0];
    float4 a1 = *(const float4*)&att[c0 + 4];
    float av[8] = {a0.x, a0.y, a0.z, a0.w, a1.x, a1.y, a1.z, a1.w};
    const float C06 = 0.6f * LOG2E, C04 = 0.4f * LOG2E;
#pragma unroll
    for (int k = 0; k < 8; ++k) { a06[k] = av[k] * C06; a04[k] = av[k] * C04; }
  }

  float acc[8];
#pragma unroll
  for (int k = 0; k < 8; ++k) acc[k] = 0.f;
  float lsum = 0.f;

#define EDGE_BODY(SRC, PVALID)                                                 \
  {                                                                            \
    uint4 raw = *(const uint4*)&xl[(size_t)(unsigned)(SRC)*128 + c0];          \
    const __half* hp = (const __half*)&raw;                                    \
    float e = 0.f;                                                             \
    _Pragma("unroll") for (int k = 0; k < 8; ++k) {                            \
      float t = __half2float(hp[k]) + fxr[k];                                  \
      e = fmaf(a06[k], t, e);                                                  \
      e = fmaf(a04[k], fabsf(t), e);                                           \
    }                                                                          \
    e += __shfl_xor(e, 1);                                                     \
    e += __shfl_xor(e, 2);                                                     \
    float p = (PVALID) ? __builtin_amdgcn_exp2f(e) : 0.f;                      \
    lsum += p;                                                                 \
    _Pragma("unroll") for (int k = 0; k < 8; ++k)                              \
        acc[k] = fmaf(p, __half2float(hp[k]), acc[k]);                         \
  }

  int beg = row_start[node], end = row_start[node + 1];
  int deg = end - beg;  // includes self
  int fullEnd = beg + (deg & ~15);

  for (int base = beg; base < fullEnd; base += 16) {
    int b0 = base + 4 * slot;
    int s0 = csr[b0], s1 = csr[b0 + 1], s2 = csr[b0 + 2], s3 = csr[b0 + 3];
    EDGE_BODY(s0, true);
    EDGE_BODY(s1, true);
    EDGE_BODY(s2, true);
    EDGE_BODY(s3, true);
  }
  for (int base = fullEnd; base < end; base += 4) {  // csr padded by 16
    int idx = base + slot;
    int src = csr[idx];
    EDGE_BODY(src, idx < end);
  }
#undef EDGE_BODY

  // merge the 4 slots (same channels live in lanes with equal l15)
  lsum += __shfl_xor(lsum, 16);
  lsum += __shfl_xor(lsum, 32);
#pragma unroll
  for (int k = 0; k < 8; ++k) {
    acc[k] += __shfl_xor(acc[k], 16);
    acc[k] += __shfl_xor(acc[k], 32);
  }

  if (slot == 0) {
    float4 b0v = *(const float4*)&bias[c0];
    float4 b1v = *(const float4*)&bias[c0 + 4];
    float bv[8] = {b0v.x, b0v.y, b0v.z, b0v.w, b1v.x, b1v.y, b1v.z, b1v.w};
    float inv = 1.f / (lsum + 1e-16f);
    float o[8];
#pragma unroll
    for (int k = 0; k < 8; ++k) {
      float v = fmaf(acc[k], inv, bv[k]);
      o[k] = fmaf(0.495f, fabsf(v), 0.505f * v);  // leaky 0.01
    }
    if (ofp) {
      *(float4*)&ofp[(size_t)node * 128 + c0] = make_float4(o[0], o[1], o[2], o[3]);
      *(float4*)&ofp[(size_t)node * 128 + c0 + 4] = make_float4(o[4], o[5], o[6], o[7]);
    }
    if (oh16) {
      ushort4 ha, hb;
      ha.x = __half_as_ushort(__float2half(o[0]));
      ha.y = __half_as_ushort(__float2half(o[1]));
      ha.z = __half_as_ushort(__float2half(o[2]));
      ha.w = __half_as_ushort(__float2half(o[3]));
      hb.x = __half_as_ushort(__float2half(o[4]));
      hb.y = __half_as_ushort(__float2half(o[5]));
      hb.z = __half_as_ushort(__float2half(o[6]));
      hb.w = __half_as_ushort(__float2half(o[7]));
      *(ushort4*)&oh16[(size_t)node * 128 + c0] = ha;
      *(ushort4*)&oh16[(size_t)node * 128 + c0 + 4] = hb;
    }
  }
}

// ------------------------------ classifier ---------------------------------
__global__ __launch_bounds__(256) void classifier_kernel(const float4* __restrict__ h4,
                                                         const float* __restrict__ Wc,
                                                         const float* __restrict__ bc,
                                                         float* __restrict__ logits,
                                                         int n) {
  __shared__ float sW[2048];
  __shared__ float sb[16];
  int t = threadIdx.x;
#pragma unroll
  for (int i = 0; i < 8; ++i) sW[t + i * 256] = Wc[t + i * 256];
  if (t < 16) sb[t] = bc[t];
  __syncthreads();
  int node = blockIdx.x * 256 + t;
  if (node >= n) return;
  float acc[16];
#pragma unroll
  for (int o = 0; o < 16; ++o) acc[o] = sb[o];
  for (int c4 = 0; c4 < 32; ++c4) {
    float4 hv = h4[(unsigned)node * 32 + c4];
    const float* w = &sW[c4 * 64];
#pragma unroll
    for (int o = 0; o < 16; ++o) {
      acc[o] = fmaf(hv.x, w[o], acc[o]);
      acc[o] = fmaf(hv.y, w[16 + o], acc[o]);
      acc[o] = fmaf(hv.z, w[32 + o], acc[o]);
      acc[o] = fmaf(hv.w, w[48 + o], acc[o]);
    }
  }
#pragma unroll
  for (int q = 0; q < 4; ++q)
    *(float4*)&logits[(size_t)node * 16 + q * 4] =
        make_float4(acc[q * 4], acc[q * 4 + 1], acc[q * 4 + 2], acc[q * 4 + 3]);
}

// ---------------------------------------------------------------------------

extern "C" void kernel_launch(void* const* d_in, const int* in_sizes, int n_in,
                              void* d_out, int out_size, void* d_ws, size_t ws_size,
                              hipStream_t stream) {
  const float* x    = (const float*)d_in[0];
  const int*   ei   = (const int*)d_in[1];
  const float* Wl1  = (const float*)d_in[3];
  const float* Wr1  = (const float*)d_in[4];
  const float* att1 = (const float*)d_in[5];
  const float* b1   = (const float*)d_in[6];
  const float* Wl2  = (const float*)d_in[7];
  const float* Wr2  = (const float*)d_in[8];
  const float* att2 = (const float*)d_in[9];
  const float* b2   = (const float*)d_in[10];
  const float* Wc   = (const float*)d_in[11];
  const float* bc   = (const float*)d_in[12];

  const int N = in_sizes[0] / 128;
  const int E = in_sizes[1] / 2;

  float* outp   = (float*)d_out;
  float* logits = outp;                   // N*16 fp32
  float* hout   = outp + (size_t)N * 16;  // N*128 fp32 region
  // h1 (fp16) staged in the hout region (overwritten by fp32 h2 later)
  __half* h1f16 = (__half*)hout;

  char* ws = (char*)d_ws;
  __half* xlbuf = (__half*)ws;                ws += (size_t)N * 128 * 2;
  __half* xrbuf = (__half*)ws;                ws += (size_t)N * 128 * 2;
  unsigned short* WT1h = (unsigned short*)ws; ws += 256 * 128 * 2;
  unsigned short* WT1l = (unsigned short*)ws; ws += 256 * 128 * 2;
  unsigned short* WT2h = (unsigned short*)ws; ws += 256 * 128 * 2;
  unsigned short* WT2l = (unsigned short*)ws; ws += 256 * 128 * 2;
  int* cnt       = (int*)ws;                  ws += (size_t)N * 4;
  int* row_start = (int*)ws;                  ws += (size_t)(N + 1) * 4;
  int* wpos      = (int*)ws;                  ws += (size_t)N * 4;
  int* bsum      = (int*)ws;                  ws += 256 * 4;
  int* csr       = (int*)ws;                  ws += (size_t)(E + N + 16) * 4;

  const int* esrc = ei;
  const int* edst = ei + E;

  int gN = (N + 255) / 256, gE = (E + 255) / 256;
  dim3 gGemm((N + 127) / 128, 2);
  int gAttn = (N + 3) / 4;
  int sliceSize = (N + 7) / 8;

  // CSR build (self loops embedded: counts+1, csr[beg]=node)
  zero_i32<<<gN, 256, 0, stream>>>(cnt, N);
  count_kernel<<<gE, 256, 0, stream>>>(edst, cnt, E);
  scan_blk<<<gN, 256, 0, stream>>>(cnt, row_start, bsum, N);
  scan_bsum<<<1, 256, 0, stream>>>(bsum, gN, row_start, N);
  scan_add<<<gN, 256, 0, stream>>>(row_start, bsum, wpos, csr, N, E + N);
  scatter_kernel<<<1024, 256, 0, stream>>>(esrc, edst, wpos, csr, E, sliceSize);

  // weight conversions (both layers, one dispatch)
  convert_W<<<256, 256, 0, stream>>>(Wl1, Wr1, Wl2, Wr2, WT1h, WT1l, WT2h, WT2l);

  // layer 1 (GEMM reads fp32 x, splits inline; writes fp16 xl/xr)
  gemm_mfma<IN_F32><<<gGemm, 256, 0, stream>>>(x, nullptr, WT1h, WT1l,
                                               xlbuf, xrbuf, N);
  gat_attn<<<gAttn, 256, 0, stream>>>(xlbuf, xrbuf, row_start, csr, att1, b1,
                                      nullptr, h1f16, N);

  // layer 2 (reads fp16 h1, splits inline; writes fp16 xl/xr)
  gemm_mfma<IN_F16><<<gGemm, 256, 0, stream>>>(nullptr, h1f16, WT2h, WT2l,
                                               xlbuf, xrbuf, N);
  gat_attn<<<gAttn, 256, 0, stream>>>(xlbuf, xrbuf, row_start, csr, att2, b2,
                                      hout, nullptr, N);

  // classifier
  classifier_kernel<<<(N + 255) / 256, 256, 0, stream>>>((const float4*)hout, Wc, bc,
                                                         logits, N);
}